// Round 20
// baseline (331.171 us; speedup 1.0000x reference)
//
#include <hip/hip_runtime.h>
#include <math.h>

#define NN 10000
#define NE 40000
#define NGRAPH 64
#define HID 64
#define EDIM 16
#define NLAYERS 3

#define NRT 625            // row tiles (16 nodes each)
#define NCT 260            // col tiles: 4096 (B) + 64 (C from b2)
#define WFRAG 512          // shorts per fragment-slot (64 lanes x 8)
#define PWL ((size_t)NCT * 2 * 2 * WFRAG)   // packed W shorts per layer (split-2)

#define GN 16              // nodes per fused group
#define KPAD 68            // k-stride in Bt (floats)
#define JSTR (16 * KPAD + 4)   // 1092: j-stride (bank-rotating)

typedef __attribute__((ext_vector_type(8))) short bf8v;
typedef __attribute__((ext_vector_type(4))) float f32x4;

__device__ __forceinline__ float silu_f(float x) { return x / (1.f + expf(-x)); }

__device__ __forceinline__ unsigned short f2bf(float f) {
    unsigned int u = __float_as_uint(f);
    u += 0x7fff + ((u >> 16) & 1);
    return (unsigned short)(u >> 16);
}
__device__ __forceinline__ float bf2f(unsigned short s) {
    return __uint_as_float(((unsigned int)s) << 16);
}
// split-2: v ~= hi + lo, residual ~2^-16 rel; 3 product terms -> out err ~1e-7
// << 1.86e-6 threshold (measured absmax 0.0 in r19).
__device__ __forceinline__ void split2f(float v, short& a, short& b) {
    unsigned short u1 = f2bf(v);      float f1 = bf2f(u1);
    unsigned short u2 = f2bf(v - f1);
    a = (short)u1; b = (short)u2;
}

// ---------------- small row GEMM ----------------
template<int K, bool DO_SILU, bool HAS_BIAS>
__global__ __launch_bounds__(256)
void k_rowmm(const float* __restrict__ A, const float* __restrict__ W,
             const float* __restrict__ bias, float* __restrict__ out, int M) {
    __shared__ float Ws[K * 64];
    __shared__ float As[4 * K];
    const int tid = threadIdx.x;
    for (int idx = tid; idx < K * 64; idx += 256) Ws[idx] = W[idx];
    const int r0 = blockIdx.x * 4;
    for (int idx = tid; idx < 4 * K; idx += 256) {
        int r = r0 + idx / K;
        As[idx] = (r < M) ? A[(size_t)r * K + (idx % K)] : 0.f;
    }
    __syncthreads();
    const int rr = tid >> 6, c = tid & 63;
    const int r = r0 + rr;
    if (r >= M) return;
    float s = HAS_BIAS ? bias[c] : 0.f;
#pragma unroll
    for (int k = 0; k < K; k++) s += As[rr * K + k] * Ws[k * 64 + c];
    if (DO_SILU) s = silu_f(s);
    out[(size_t)r * 64 + c] = s;
}

// ---------------- batched edge-MLP for ALL layers ----------------
__global__ __launch_bounds__(256)
void k_gmm3(const float* __restrict__ ea, const float* __restrict__ ew1,
            const float* __restrict__ eb1, float* __restrict__ g3) {
    const int l = blockIdx.y;
    const float* W = ew1 + (size_t)l * EDIM * 64;
    const float* bias = eb1 + (size_t)l * 64;
    float* out = g3 + (size_t)l * NE * 64;
    __shared__ float Ws[EDIM * 64];
    __shared__ float As[4 * EDIM];
    const int tid = threadIdx.x;
    for (int idx = tid; idx < EDIM * 64; idx += 256) Ws[idx] = W[idx];
    const int r0 = blockIdx.x * 4;
    if (tid < 4 * EDIM) As[tid] = ea[(size_t)r0 * EDIM + tid];
    __syncthreads();
    const int rr = tid >> 6, c = tid & 63;
    float s = bias[c];
#pragma unroll
    for (int k = 0; k < EDIM; k++) s += As[rr * EDIM + k] * Ws[k * 64 + c];
    out[(size_t)(r0 + rr) * 64 + c] = silu_f(s);
}

// ---------------- degree histograms ----------------
__global__ void k_hist(const int* __restrict__ ei, int* __restrict__ cnt_s,
                       int* __restrict__ cnt_d) {
    int e = blockIdx.x * 256 + threadIdx.x;
    if (e >= NE) return;
    atomicAdd(&cnt_s[ei[e]], 1);
    atomicAdd(&cnt_d[ei[NE + e]], 1);
}

// ---------------- single-block: both scans + invdeg ----------------
__global__ __launch_bounds__(1024)
void k_scan2(const int* __restrict__ cnt_s, const int* __restrict__ cnt_d,
             int* __restrict__ off_s, int* __restrict__ off_d,
             int* __restrict__ cur_s, int* __restrict__ cur_d,
             float* __restrict__ invd) {
    __shared__ int part[1024];
    const int t = threadIdx.x;
    const int CH = (NN + 1023) / 1024;
    const int base0 = t * CH;
#pragma unroll
    for (int pass = 0; pass < 2; ++pass) {
        const int* cnt = pass ? cnt_d : cnt_s;
        int* off = pass ? off_d : off_s;
        int* cur = pass ? cur_d : cur_s;
        int s = 0;
        for (int i = 0; i < CH; i++) {
            int idx = base0 + i;
            if (idx < NN) s += cnt[idx];
        }
        part[t] = s;
        __syncthreads();
        for (int d = 1; d < 1024; d <<= 1) {
            int v = (t >= d) ? part[t - d] : 0;
            __syncthreads();
            part[t] += v;
            __syncthreads();
        }
        int run = (t == 0) ? 0 : part[t - 1];
        for (int i = 0; i < CH; i++) {
            int idx = base0 + i;
            if (idx < NN) {
                off[idx] = run;
                int c = cnt[idx];
                if (pass) invd[idx] = (c > 0) ? 1.f / (float)c : 0.f;
                run += c;
                cur[idx] = 0;
            }
        }
        if (t == 1023) off[NN] = run;
        __syncthreads();
    }
}

__global__ void k_fill(const int* __restrict__ keys, const int* __restrict__ off,
                       int* __restrict__ cur, int* __restrict__ eid) {
    int e = blockIdx.x * 256 + threadIdx.x;
    if (e >= NE) return;
    int s = keys[e];
    int p = atomicAdd(&cur[s], 1);
    eid[off[s] + p] = e;
}

// ---------------- pack w2 (+b2 as cols 4096..4159) into MFMA B-fragments ----------
__global__ __launch_bounds__(128)
void k_packw(const float* __restrict__ ew2, const float* __restrict__ eb2,
             short* __restrict__ pw) {
    const int ct = blockIdx.x;
    const int lay = blockIdx.y;
    const int t = threadIdx.x;
    const int l = t & 63, ks = t >> 6;
    const int col = ct * 16 + (l & 15);
    const int i0 = ks * 32 + ((l >> 4) << 3);
    bf8v v1, v2;
#pragma unroll
    for (int tt = 0; tt < 8; ++tt) {
        const int i = i0 + tt;
        float v;
        if (col < 4096)
            v = ew2[(size_t)lay * 262144 + (size_t)(col >> 6) * 4096 + i * 64 + (col & 63)];
        else
            v = eb2[(size_t)lay * 4096 + i * 64 + (col - 4096)];
        short a, b;
        split2f(v, a, b);
        v1[tt] = a; v2[tt] = b;
    }
    short* dst = pw + ((((size_t)lay * NCT + ct) * 2 + ks) * 2) * WFRAG + l * 8;
    *reinterpret_cast<bf8v*>(dst)       = v1;
    *reinterpret_cast<bf8v*>(dst + 512) = v2;
}

// ---------------- FUSED v7: in-kernel A-frags + direct j (no packh, no j-search) --
__global__ __launch_bounds__(512, 4)
void k_msgfused(const float* __restrict__ h, const short* __restrict__ pw,
                const float* __restrict__ g, const int* __restrict__ ei,
                const int* __restrict__ csr_off, const int* __restrict__ csr_eid,
                float* __restrict__ msg) {
    __shared__ float Bt[16 * JSTR];
    __shared__ float C_s[16 * 16];

    const int grp = blockIdx.x, q = blockIdx.y;
    const int n0  = grp * GN;
    const int lane = threadIdx.x & 63;
    const int wid  = threadIdx.x >> 6;     // 0..7

    // A fragments (hi, lo) computed in-kernel from h (replaces k_packh)
    bf8v A[2][2];
    {
        const float* hp = h + (size_t)(n0 + (lane & 15)) * 64;
#pragma unroll
        for (int ks = 0; ks < 2; ++ks) {
            const int i0 = ks * 32 + ((lane >> 4) << 3);
            bf8v hi, lo;
#pragma unroll
            for (int tt = 0; tt < 8; ++tt) {
                short a, b;
                split2f(hp[i0 + tt], a, b);
                hi[tt] = a; lo[tt] = b;
            }
            A[ks][0] = hi; A[ks][1] = lo;
        }
    }

    const int oq_w = lane & 15;            // o' within quarter (C/D col)
    const int jb   = (lane >> 4) << 2;     // C/D row base

    // ---- MFMA phase: wave wid covers k = wid*8 .. +8 ----
#pragma unroll 2
    for (int kk = 0; kk < 8; ++kk) {
        const int k = wid * 8 + kk;
        const int ct = k * 4 + q;
        bf8v Bf[2][2];
#pragma unroll
        for (int ks = 0; ks < 2; ++ks)
#pragma unroll
            for (int sp = 0; sp < 2; ++sp)
                Bf[ks][sp] = *reinterpret_cast<const bf8v*>(
                    pw + (((size_t)ct * 2 + ks) * 2 + sp) * WFRAG + lane * 8);
        f32x4 acc = {0.f, 0.f, 0.f, 0.f};
#pragma unroll
        for (int ks = 0; ks < 2; ++ks) {
            acc = __builtin_amdgcn_mfma_f32_16x16x32_bf16(A[ks][0], Bf[ks][0], acc, 0, 0, 0);
            acc = __builtin_amdgcn_mfma_f32_16x16x32_bf16(A[ks][1], Bf[ks][0], acc, 0, 0, 0);
            acc = __builtin_amdgcn_mfma_f32_16x16x32_bf16(A[ks][0], Bf[ks][1], acc, 0, 0, 0);
        }
#pragma unroll
        for (int r = 0; r < 4; ++r)
            Bt[(jb + r) * JSTR + oq_w * KPAD + k] = acc[r];
    }
    if (wid == 7) {   // ---- C tile (b2 cols) ----
        const int ct = 256 + q;
        bf8v Bf[2][2];
#pragma unroll
        for (int ks = 0; ks < 2; ++ks)
#pragma unroll
            for (int sp = 0; sp < 2; ++sp)
                Bf[ks][sp] = *reinterpret_cast<const bf8v*>(
                    pw + (((size_t)ct * 2 + ks) * 2 + sp) * WFRAG + lane * 8);
        f32x4 acc = {0.f, 0.f, 0.f, 0.f};
#pragma unroll
        for (int ks = 0; ks < 2; ++ks) {
            acc = __builtin_amdgcn_mfma_f32_16x16x32_bf16(A[ks][0], Bf[ks][0], acc, 0, 0, 0);
            acc = __builtin_amdgcn_mfma_f32_16x16x32_bf16(A[ks][1], Bf[ks][0], acc, 0, 0, 0);
            acc = __builtin_amdgcn_mfma_f32_16x16x32_bf16(A[ks][0], Bf[ks][1], acc, 0, 0, 0);
        }
#pragma unroll
        for (int r = 0; r < 4; ++r)
            C_s[(jb + r) * 16 + oq_w] = acc[r];
    }

    const int P0 = csr_off[n0];                 // uniform scalar loads
    const int Etot = csr_off[n0 + GN] - P0;
    __syncthreads();

    // ---- edge phase: 16 lanes per edge; 32 slots in flight; j = src - n0 ----
    const int oq = threadIdx.x & 15;
    const int eq = threadIdx.x >> 4;       // 0..31
    for (int slot = eq; slot < Etot; slot += 32) {
        const int e = csr_eid[P0 + slot];
        const int j = ei[e] - n0;          // direct src lookup (was 15-cmp chain)
        const float* grow = g + (size_t)e * 64;
        const float* Bj = Bt + j * JSTR + oq * KPAD;
        float m = C_s[j * 16 + oq];
#pragma unroll
        for (int k4 = 0; k4 < 16; ++k4) {
            const float4 gv = *(const float4*)(grow + k4 * 4);   // quad-broadcast
            const float4 bv = *(const float4*)(Bj + k4 * 4);
            m += gv.x * bv.x + gv.y * bv.y + gv.z * bv.z + gv.w * bv.w;
        }
        msg[(size_t)e * 64 + q * 16 + oq] = m;
    }
}

// ---------------- gather by dst + root GEMM + silu (8 rows/block) ----------------
__global__ __launch_bounds__(256)
void k_aggfin(const float* __restrict__ h, const float* __restrict__ msg,
              const int* __restrict__ off2, const int* __restrict__ eid2,
              const float* __restrict__ invd, const float* __restrict__ rw,
              const float* __restrict__ cb, float* __restrict__ hout) {
    __shared__ float Ws[64 * 64];
    __shared__ float As[8 * 64];
    __shared__ int eoff[9];
    const int tid = threadIdx.x;
    for (int idx = tid; idx < 64 * 64; idx += 256) Ws[idx] = rw[idx];
    const int r0 = blockIdx.x * 8;
    for (int idx = tid; idx < 8 * 64; idx += 256) As[idx] = h[(size_t)r0 * 64 + idx];
    if (tid < 9) eoff[tid] = off2[r0 + tid];
    __syncthreads();
    const int rr = tid >> 6, c = tid & 63;
#pragma unroll
    for (int half = 0; half < 2; ++half) {
        const int lr = half * 4 + rr;
        const int r = r0 + lr;
        float a = 0.f;
        for (int p = eoff[lr]; p < eoff[lr + 1]; ++p) {
            a += msg[(size_t)eid2[p] * 64 + c];
        }
        float s = cb[c] + a * invd[r];
        const float* Ar = As + lr * 64;
#pragma unroll
        for (int k = 0; k < 64; k++) s += Ar[k] * Ws[k * 64 + c];
        hout[(size_t)r * 64 + c] = silu_f(s);
    }
}

// ---------------- fused mean-pool + head MLP ----------------
__global__ __launch_bounds__(256)
void k_poolhead(const float* __restrict__ h, const int* __restrict__ batch,
                const float* __restrict__ w1, const float* __restrict__ b1,
                const float* __restrict__ w2, const float* __restrict__ b2,
                float* __restrict__ out) {
    __shared__ float part[4 * 64];
    __shared__ float hrow[64];
    const int gidx = blockIdx.x;
    const int tid = threadIdx.x;
    const int r = tid >> 6, o = tid & 63;
    int lo = 0, hi = NN;
    while (lo < hi) { int m = (lo + hi) >> 1; if (batch[m] < gidx) lo = m + 1; else hi = m; }
    const int beg = lo;
    hi = NN;
    while (lo < hi) { int m = (lo + hi) >> 1; if (batch[m] < gidx + 1) lo = m + 1; else hi = m; }
    const int end = lo;
    float acc = 0.f;
    for (int n = beg + r; n < end; n += 4) acc += h[(size_t)n * 64 + o];
    part[r * 64 + o] = acc;
    __syncthreads();
    if (tid < 64) {
        const int cnt = end - beg;
        const float inv = (cnt > 0) ? 1.f / (float)cnt : 1.f;
        hrow[tid] = (part[tid] + part[64 + tid] + part[128 + tid] + part[192 + tid]) * inv;
    }
    __syncthreads();
    if (tid < 64) {
        float s = b1[tid];
#pragma unroll
        for (int k = 0; k < 64; ++k) s += hrow[k] * w1[k * 64 + tid];
        s = silu_f(s);
        float v = s * w2[tid];
#pragma unroll
        for (int d = 32; d > 0; d >>= 1) v += __shfl_down(v, d);
        if (tid == 0) out[gidx] = v + b2[0];
    }
}

extern "C" void kernel_launch(void* const* d_in, const int* in_sizes, int n_in,
                              void* d_out, int out_size, void* d_ws, size_t ws_size,
                              hipStream_t stream) {
    const float* x     = (const float*)d_in[0];
    const float* ea    = (const float*)d_in[1];
    const int*   ei    = (const int*)  d_in[2];
    const int*   batch = (const int*)  d_in[3];
    const float* pw    = (const float*)d_in[4];
    const float* pb    = (const float*)d_in[5];
    const float* ew1   = (const float*)d_in[6];
    const float* eb1   = (const float*)d_in[7];
    const float* ew2   = (const float*)d_in[8];
    const float* eb2   = (const float*)d_in[9];
    const float* rw    = (const float*)d_in[10];
    const float* cb    = (const float*)d_in[11];
    const float* hw1   = (const float*)d_in[12];
    const float* hb1   = (const float*)d_in[13];
    const float* hw2   = (const float*)d_in[14];
    const float* hb2   = (const float*)d_in[15];
    float* out = (float*)d_out;

    float* ws = (float*)d_ws;
    size_t off = 0;
    auto alloc = [&](size_t n) {
        float* p = ws + off;
        off += (n + 63) & ~(size_t)63;
        return p;
    };
    float* hA   = alloc((size_t)NN * 64);
    float* hBuf = alloc((size_t)NN * 64);
    float* msg  = alloc((size_t)NE * 64);
    float* invd = alloc(NN);
    int* off_s = (int*)alloc(NN + 1);
    int* off_d = (int*)alloc(NN + 1);
    int* cnt_s = (int*)alloc(NN);
    int* cnt_d = (int*)alloc(NN);
    int* cur_s = (int*)alloc(NN);
    int* cur_d = (int*)alloc(NN);
    int* eid_s = (int*)alloc(NE);
    int* eid_d = (int*)alloc(NE);
    short* packW = (short*)alloc(3 * PWL / 2 + 64);

    const size_t needG3 = (size_t)3 * NE * 64;
    bool batchG = (off + needG3 + 128) * sizeof(float) <= ws_size;
    float* gbuf = alloc(batchG ? needG3 : (size_t)NE * 64);

    hipMemsetAsync(cnt_s, 0, NN * sizeof(int), stream);
    hipMemsetAsync(cnt_d, 0, NN * sizeof(int), stream);

    k_hist<<<dim3((NE + 255) / 256), dim3(256), 0, stream>>>(ei, cnt_s, cnt_d);
    k_scan2<<<dim3(1), dim3(1024), 0, stream>>>(cnt_s, cnt_d, off_s, off_d,
                                                cur_s, cur_d, invd);
    k_fill<<<dim3((NE + 255) / 256), dim3(256), 0, stream>>>(ei, off_s, cur_s, eid_s);
    k_fill<<<dim3((NE + 255) / 256), dim3(256), 0, stream>>>(ei + NE, off_d, cur_d, eid_d);

    k_packw<<<dim3(NCT, 3), dim3(128), 0, stream>>>(ew2, eb2, packW);

    k_rowmm<64, false, true><<<dim3(NN / 4), dim3(256), 0, stream>>>(x, pw, pb, hA, NN);

    if (batchG) {
        k_gmm3<<<dim3(NE / 4, 3), dim3(256), 0, stream>>>(ea, ew1, eb1, gbuf);
    }

    float* hcur = hA;
    float* hnxt = hBuf;
    for (int l = 0; l < NLAYERS; l++) {
        float* gl = batchG ? gbuf + (size_t)l * NE * 64 : gbuf;
        if (!batchG) {
            k_rowmm<16, true, true><<<dim3(NE / 4), dim3(256), 0, stream>>>(
                ea, ew1 + (size_t)l * EDIM * 64, eb1 + (size_t)l * 64, gl, NE);
        }
        k_msgfused<<<dim3(NRT, 4), dim3(512), 0, stream>>>(
            hcur, packW + (size_t)l * PWL, gl, ei, off_s, eid_s, msg);
        k_aggfin<<<dim3(NN / 8), dim3(256), 0, stream>>>(
            hcur, msg, off_d, eid_d, invd, rw + (size_t)l * 64 * 64,
            cb + (size_t)l * 64, hnxt);
        float* t = hcur; hcur = hnxt; hnxt = t;
    }

    k_poolhead<<<dim3(NGRAPH), dim3(256), 0, stream>>>(
        hcur, batch, hw1, hb1, hw2, hb2, out);
}

// Round 21
// 322.573 us; speedup vs baseline: 1.0267x; 1.0267x over previous
//
#include <hip/hip_runtime.h>
#include <math.h>

#define NN 10000
#define NE 40000
#define NGRAPH 64
#define HID 64
#define EDIM 16
#define NLAYERS 3

#define NRT 625            // row tiles (16 nodes each)
#define NCT 260            // col tiles: 4096 (B) + 64 (C from b2)
#define WFRAG 512          // shorts per fragment-slot (64 lanes x 8)
#define PWL ((size_t)NCT * 2 * 2 * WFRAG)   // packed W shorts per layer (split-2)

#define GN 16              // nodes per fused group
#define KPAD 68            // k-stride in Bt (floats)
#define JSTR (16 * KPAD + 4)   // 1092: j-stride (bank-rotating)

typedef __attribute__((ext_vector_type(8))) short bf8v;
typedef __attribute__((ext_vector_type(4))) float f32x4;

__device__ __forceinline__ float silu_f(float x) { return x / (1.f + expf(-x)); }

__device__ __forceinline__ unsigned short f2bf(float f) {
    unsigned int u = __float_as_uint(f);
    u += 0x7fff + ((u >> 16) & 1);
    return (unsigned short)(u >> 16);
}
__device__ __forceinline__ float bf2f(unsigned short s) {
    return __uint_as_float(((unsigned int)s) << 16);
}
// split-2: v ~= hi + lo, residual ~2^-16 rel; 3 product terms -> out err ~1e-7
// << 1.86e-6 threshold (measured absmax 0.0 in r19).
__device__ __forceinline__ void split2f(float v, short& a, short& b) {
    unsigned short u1 = f2bf(v);      float f1 = bf2f(u1);
    unsigned short u2 = f2bf(v - f1);
    a = (short)u1; b = (short)u2;
}

// ---------------- small row GEMM ----------------
template<int K, bool DO_SILU, bool HAS_BIAS>
__global__ __launch_bounds__(256)
void k_rowmm(const float* __restrict__ A, const float* __restrict__ W,
             const float* __restrict__ bias, float* __restrict__ out, int M) {
    __shared__ float Ws[K * 64];
    __shared__ float As[4 * K];
    const int tid = threadIdx.x;
    for (int idx = tid; idx < K * 64; idx += 256) Ws[idx] = W[idx];
    const int r0 = blockIdx.x * 4;
    for (int idx = tid; idx < 4 * K; idx += 256) {
        int r = r0 + idx / K;
        As[idx] = (r < M) ? A[(size_t)r * K + (idx % K)] : 0.f;
    }
    __syncthreads();
    const int rr = tid >> 6, c = tid & 63;
    const int r = r0 + rr;
    if (r >= M) return;
    float s = HAS_BIAS ? bias[c] : 0.f;
#pragma unroll
    for (int k = 0; k < K; k++) s += As[rr * K + k] * Ws[k * 64 + c];
    if (DO_SILU) s = silu_f(s);
    out[(size_t)r * 64 + c] = s;
}

// ---------------- batched edge-MLP for ALL layers ----------------
__global__ __launch_bounds__(256)
void k_gmm3(const float* __restrict__ ea, const float* __restrict__ ew1,
            const float* __restrict__ eb1, float* __restrict__ g3) {
    const int l = blockIdx.y;
    const float* W = ew1 + (size_t)l * EDIM * 64;
    const float* bias = eb1 + (size_t)l * 64;
    float* out = g3 + (size_t)l * NE * 64;
    __shared__ float Ws[EDIM * 64];
    __shared__ float As[4 * EDIM];
    const int tid = threadIdx.x;
    for (int idx = tid; idx < EDIM * 64; idx += 256) Ws[idx] = W[idx];
    const int r0 = blockIdx.x * 4;
    if (tid < 4 * EDIM) As[tid] = ea[(size_t)r0 * EDIM + tid];
    __syncthreads();
    const int rr = tid >> 6, c = tid & 63;
    float s = bias[c];
#pragma unroll
    for (int k = 0; k < EDIM; k++) s += As[rr * EDIM + k] * Ws[k * 64 + c];
    out[(size_t)(r0 + rr) * 64 + c] = silu_f(s);
}

// ---------------- degree histograms ----------------
__global__ void k_hist(const int* __restrict__ ei, int* __restrict__ cnt_s,
                       int* __restrict__ cnt_d) {
    int e = blockIdx.x * 256 + threadIdx.x;
    if (e >= NE) return;
    atomicAdd(&cnt_s[ei[e]], 1);
    atomicAdd(&cnt_d[ei[NE + e]], 1);
}

// ---------------- single-block: both scans + invdeg ----------------
__global__ __launch_bounds__(1024)
void k_scan2(const int* __restrict__ cnt_s, const int* __restrict__ cnt_d,
             int* __restrict__ off_s, int* __restrict__ off_d,
             int* __restrict__ cur_s, int* __restrict__ cur_d,
             float* __restrict__ invd) {
    __shared__ int part[1024];
    const int t = threadIdx.x;
    const int CH = (NN + 1023) / 1024;
    const int base0 = t * CH;
#pragma unroll
    for (int pass = 0; pass < 2; ++pass) {
        const int* cnt = pass ? cnt_d : cnt_s;
        int* off = pass ? off_d : off_s;
        int* cur = pass ? cur_d : cur_s;
        int s = 0;
        for (int i = 0; i < CH; i++) {
            int idx = base0 + i;
            if (idx < NN) s += cnt[idx];
        }
        part[t] = s;
        __syncthreads();
        for (int d = 1; d < 1024; d <<= 1) {
            int v = (t >= d) ? part[t - d] : 0;
            __syncthreads();
            part[t] += v;
            __syncthreads();
        }
        int run = (t == 0) ? 0 : part[t - 1];
        for (int i = 0; i < CH; i++) {
            int idx = base0 + i;
            if (idx < NN) {
                off[idx] = run;
                int c = cnt[idx];
                if (pass) invd[idx] = (c > 0) ? 1.f / (float)c : 0.f;
                run += c;
                cur[idx] = 0;
            }
        }
        if (t == 1023) off[NN] = run;
        __syncthreads();
    }
}

__global__ void k_fill(const int* __restrict__ keys, const int* __restrict__ off,
                       int* __restrict__ cur, int* __restrict__ eid) {
    int e = blockIdx.x * 256 + threadIdx.x;
    if (e >= NE) return;
    int s = keys[e];
    int p = atomicAdd(&cur[s], 1);
    eid[off[s] + p] = e;
}

// ---------------- pack w2 (+b2 as cols 4096..4159) into MFMA B-fragments ----------
__global__ __launch_bounds__(128)
void k_packw(const float* __restrict__ ew2, const float* __restrict__ eb2,
             short* __restrict__ pw) {
    const int ct = blockIdx.x;
    const int lay = blockIdx.y;
    const int t = threadIdx.x;
    const int l = t & 63, ks = t >> 6;
    const int col = ct * 16 + (l & 15);
    const int i0 = ks * 32 + ((l >> 4) << 3);
    bf8v v1, v2;
#pragma unroll
    for (int tt = 0; tt < 8; ++tt) {
        const int i = i0 + tt;
        float v;
        if (col < 4096)
            v = ew2[(size_t)lay * 262144 + (size_t)(col >> 6) * 4096 + i * 64 + (col & 63)];
        else
            v = eb2[(size_t)lay * 4096 + i * 64 + (col - 4096)];
        short a, b;
        split2f(v, a, b);
        v1[tt] = a; v2[tt] = b;
    }
    short* dst = pw + ((((size_t)lay * NCT + ct) * 2 + ks) * 2) * WFRAG + l * 8;
    *reinterpret_cast<bf8v*>(dst)       = v1;
    *reinterpret_cast<bf8v*>(dst + 512) = v2;
}

// ---------------- pack h into MFMA A-fragments (per layer) ----------------
__global__ __launch_bounds__(128)
void k_packh(const float* __restrict__ h, short* __restrict__ ph) {
    const int rt = blockIdx.x;
    const int t = threadIdx.x;
    const int l = t & 63, ks = t >> 6;
    const int row = rt * 16 + (l & 15);
    const int i0 = ks * 32 + ((l >> 4) << 3);
    const float* hp = h + (size_t)row * 64 + i0;
    bf8v v1, v2;
#pragma unroll
    for (int tt = 0; tt < 8; ++tt) {
        short a, b;
        split2f(hp[tt], a, b);
        v1[tt] = a; v2[tt] = b;
    }
    short* dst = ph + (((size_t)rt * 2 + ks) * 2) * WFRAG + l * 8;
    *reinterpret_cast<bf8v*>(dst)       = v1;
    *reinterpret_cast<bf8v*>(dst + 512) = v2;
}

// ---------------- FUSED v8: r19 structure (packh, split-2) + direct-j edge phase --
__global__ __launch_bounds__(512, 4)
void k_msgfused(const short* __restrict__ ph, const short* __restrict__ pw,
                const float* __restrict__ g, const int* __restrict__ ei,
                const int* __restrict__ csr_off, const int* __restrict__ csr_eid,
                float* __restrict__ msg) {
    __shared__ float Bt[16 * JSTR];
    __shared__ float C_s[16 * 16];

    const int grp = blockIdx.x, q = blockIdx.y;
    const int n0  = grp * GN;
    const int lane = threadIdx.x & 63;
    const int wid  = threadIdx.x >> 6;     // 0..7

    // A fragments (hi, lo) for this row-tile
    bf8v A[2][2];
#pragma unroll
    for (int ks = 0; ks < 2; ++ks)
#pragma unroll
        for (int sp = 0; sp < 2; ++sp)
            A[ks][sp] = *reinterpret_cast<const bf8v*>(
                ph + (((size_t)grp * 2 + ks) * 2 + sp) * WFRAG + lane * 8);

    const int oq_w = lane & 15;            // o' within quarter (C/D col)
    const int jb   = (lane >> 4) << 2;     // C/D row base

    // ---- MFMA phase: wave wid covers k = wid*8 .. +8 ----
#pragma unroll 2
    for (int kk = 0; kk < 8; ++kk) {
        const int k = wid * 8 + kk;
        const int ct = k * 4 + q;
        bf8v Bf[2][2];
#pragma unroll
        for (int ks = 0; ks < 2; ++ks)
#pragma unroll
            for (int sp = 0; sp < 2; ++sp)
                Bf[ks][sp] = *reinterpret_cast<const bf8v*>(
                    pw + (((size_t)ct * 2 + ks) * 2 + sp) * WFRAG + lane * 8);
        f32x4 acc = {0.f, 0.f, 0.f, 0.f};
#pragma unroll
        for (int ks = 0; ks < 2; ++ks) {
            acc = __builtin_amdgcn_mfma_f32_16x16x32_bf16(A[ks][0], Bf[ks][0], acc, 0, 0, 0);
            acc = __builtin_amdgcn_mfma_f32_16x16x32_bf16(A[ks][1], Bf[ks][0], acc, 0, 0, 0);
            acc = __builtin_amdgcn_mfma_f32_16x16x32_bf16(A[ks][0], Bf[ks][1], acc, 0, 0, 0);
        }
#pragma unroll
        for (int r = 0; r < 4; ++r)
            Bt[(jb + r) * JSTR + oq_w * KPAD + k] = acc[r];
    }
    if (wid == 7) {   // ---- C tile (b2 cols) ----
        const int ct = 256 + q;
        bf8v Bf[2][2];
#pragma unroll
        for (int ks = 0; ks < 2; ++ks)
#pragma unroll
            for (int sp = 0; sp < 2; ++sp)
                Bf[ks][sp] = *reinterpret_cast<const bf8v*>(
                    pw + (((size_t)ct * 2 + ks) * 2 + sp) * WFRAG + lane * 8);
        f32x4 acc = {0.f, 0.f, 0.f, 0.f};
#pragma unroll
        for (int ks = 0; ks < 2; ++ks) {
            acc = __builtin_amdgcn_mfma_f32_16x16x32_bf16(A[ks][0], Bf[ks][0], acc, 0, 0, 0);
            acc = __builtin_amdgcn_mfma_f32_16x16x32_bf16(A[ks][1], Bf[ks][0], acc, 0, 0, 0);
            acc = __builtin_amdgcn_mfma_f32_16x16x32_bf16(A[ks][0], Bf[ks][1], acc, 0, 0, 0);
        }
#pragma unroll
        for (int r = 0; r < 4; ++r)
            C_s[(jb + r) * 16 + oq_w] = acc[r];
    }

    const int P0 = csr_off[n0];                 // uniform scalar loads
    const int Etot = csr_off[n0 + GN] - P0;
    __syncthreads();

    // ---- edge phase: 16 lanes per edge; 32 slots in flight; j = src - n0 ----
    const int oq = threadIdx.x & 15;
    const int eq = threadIdx.x >> 4;       // 0..31
    for (int slot = eq; slot < Etot; slot += 32) {
        const int e = csr_eid[P0 + slot];
        const int j = ei[e] - n0;          // direct src lookup (was 15-cmp chain)
        const float* grow = g + (size_t)e * 64;
        const float* Bj = Bt + j * JSTR + oq * KPAD;
        float m = C_s[j * 16 + oq];
#pragma unroll
        for (int k4 = 0; k4 < 16; ++k4) {
            const float4 gv = *(const float4*)(grow + k4 * 4);   // quad-broadcast
            const float4 bv = *(const float4*)(Bj + k4 * 4);
            m += gv.x * bv.x + gv.y * bv.y + gv.z * bv.z + gv.w * bv.w;
        }
        msg[(size_t)e * 64 + q * 16 + oq] = m;
    }
}

// ---------------- gather by dst + root GEMM + silu (8 rows/block) ----------------
__global__ __launch_bounds__(256)
void k_aggfin(const float* __restrict__ h, const float* __restrict__ msg,
              const int* __restrict__ off2, const int* __restrict__ eid2,
              const float* __restrict__ invd, const float* __restrict__ rw,
              const float* __restrict__ cb, float* __restrict__ hout) {
    __shared__ float Ws[64 * 64];
    __shared__ float As[8 * 64];
    __shared__ int eoff[9];
    const int tid = threadIdx.x;
    for (int idx = tid; idx < 64 * 64; idx += 256) Ws[idx] = rw[idx];
    const int r0 = blockIdx.x * 8;
    for (int idx = tid; idx < 8 * 64; idx += 256) As[idx] = h[(size_t)r0 * 64 + idx];
    if (tid < 9) eoff[tid] = off2[r0 + tid];
    __syncthreads();
    const int rr = tid >> 6, c = tid & 63;
#pragma unroll
    for (int half = 0; half < 2; ++half) {
        const int lr = half * 4 + rr;
        const int r = r0 + lr;
        float a = 0.f;
        for (int p = eoff[lr]; p < eoff[lr + 1]; ++p) {
            a += msg[(size_t)eid2[p] * 64 + c];
        }
        float s = cb[c] + a * invd[r];
        const float* Ar = As + lr * 64;
#pragma unroll
        for (int k = 0; k < 64; k++) s += Ar[k] * Ws[k * 64 + c];
        hout[(size_t)r * 64 + c] = silu_f(s);
    }
}

// ---------------- fused mean-pool + head MLP ----------------
__global__ __launch_bounds__(256)
void k_poolhead(const float* __restrict__ h, const int* __restrict__ batch,
                const float* __restrict__ w1, const float* __restrict__ b1,
                const float* __restrict__ w2, const float* __restrict__ b2,
                float* __restrict__ out) {
    __shared__ float part[4 * 64];
    __shared__ float hrow[64];
    const int gidx = blockIdx.x;
    const int tid = threadIdx.x;
    const int r = tid >> 6, o = tid & 63;
    int lo = 0, hi = NN;
    while (lo < hi) { int m = (lo + hi) >> 1; if (batch[m] < gidx) lo = m + 1; else hi = m; }
    const int beg = lo;
    hi = NN;
    while (lo < hi) { int m = (lo + hi) >> 1; if (batch[m] < gidx + 1) lo = m + 1; else hi = m; }
    const int end = lo;
    float acc = 0.f;
    for (int n = beg + r; n < end; n += 4) acc += h[(size_t)n * 64 + o];
    part[r * 64 + o] = acc;
    __syncthreads();
    if (tid < 64) {
        const int cnt = end - beg;
        const float inv = (cnt > 0) ? 1.f / (float)cnt : 1.f;
        hrow[tid] = (part[tid] + part[64 + tid] + part[128 + tid] + part[192 + tid]) * inv;
    }
    __syncthreads();
    if (tid < 64) {
        float s = b1[tid];
#pragma unroll
        for (int k = 0; k < 64; ++k) s += hrow[k] * w1[k * 64 + tid];
        s = silu_f(s);
        float v = s * w2[tid];
#pragma unroll
        for (int d = 32; d > 0; d >>= 1) v += __shfl_down(v, d);
        if (tid == 0) out[gidx] = v + b2[0];
    }
}

extern "C" void kernel_launch(void* const* d_in, const int* in_sizes, int n_in,
                              void* d_out, int out_size, void* d_ws, size_t ws_size,
                              hipStream_t stream) {
    const float* x     = (const float*)d_in[0];
    const float* ea    = (const float*)d_in[1];
    const int*   ei    = (const int*)  d_in[2];
    const int*   batch = (const int*)  d_in[3];
    const float* pw    = (const float*)d_in[4];
    const float* pb    = (const float*)d_in[5];
    const float* ew1   = (const float*)d_in[6];
    const float* eb1   = (const float*)d_in[7];
    const float* ew2   = (const float*)d_in[8];
    const float* eb2   = (const float*)d_in[9];
    const float* rw    = (const float*)d_in[10];
    const float* cb    = (const float*)d_in[11];
    const float* hw1   = (const float*)d_in[12];
    const float* hb1   = (const float*)d_in[13];
    const float* hw2   = (const float*)d_in[14];
    const float* hb2   = (const float*)d_in[15];
    float* out = (float*)d_out;

    float* ws = (float*)d_ws;
    size_t off = 0;
    auto alloc = [&](size_t n) {
        float* p = ws + off;
        off += (n + 63) & ~(size_t)63;
        return p;
    };
    float* hA   = alloc((size_t)NN * 64);
    float* hBuf = alloc((size_t)NN * 64);
    float* msg  = alloc((size_t)NE * 64);
    float* invd = alloc(NN);
    int* off_s = (int*)alloc(NN + 1);
    int* off_d = (int*)alloc(NN + 1);
    int* cnt_s = (int*)alloc(NN);
    int* cnt_d = (int*)alloc(NN);
    int* cur_s = (int*)alloc(NN);
    int* cur_d = (int*)alloc(NN);
    int* eid_s = (int*)alloc(NE);
    int* eid_d = (int*)alloc(NE);
    short* packW = (short*)alloc(3 * PWL / 2 + 64);
    short* packH = (short*)alloc((size_t)NRT * 2 * 2 * WFRAG / 2 + 64);

    const size_t needG3 = (size_t)3 * NE * 64;
    bool batchG = (off + needG3 + 128) * sizeof(float) <= ws_size;
    float* gbuf = alloc(batchG ? needG3 : (size_t)NE * 64);

    hipMemsetAsync(cnt_s, 0, NN * sizeof(int), stream);
    hipMemsetAsync(cnt_d, 0, NN * sizeof(int), stream);

    k_hist<<<dim3((NE + 255) / 256), dim3(256), 0, stream>>>(ei, cnt_s, cnt_d);
    k_scan2<<<dim3(1), dim3(1024), 0, stream>>>(cnt_s, cnt_d, off_s, off_d,
                                                cur_s, cur_d, invd);
    k_fill<<<dim3((NE + 255) / 256), dim3(256), 0, stream>>>(ei, off_s, cur_s, eid_s);
    k_fill<<<dim3((NE + 255) / 256), dim3(256), 0, stream>>>(ei + NE, off_d, cur_d, eid_d);

    k_packw<<<dim3(NCT, 3), dim3(128), 0, stream>>>(ew2, eb2, packW);

    k_rowmm<64, false, true><<<dim3(NN / 4), dim3(256), 0, stream>>>(x, pw, pb, hA, NN);

    if (batchG) {
        k_gmm3<<<dim3(NE / 4, 3), dim3(256), 0, stream>>>(ea, ew1, eb1, gbuf);
    }

    float* hcur = hA;
    float* hnxt = hBuf;
    for (int l = 0; l < NLAYERS; l++) {
        float* gl = batchG ? gbuf + (size_t)l * NE * 64 : gbuf;
        if (!batchG) {
            k_rowmm<16, true, true><<<dim3(NE / 4), dim3(256), 0, stream>>>(
                ea, ew1 + (size_t)l * EDIM * 64, eb1 + (size_t)l * 64, gl, NE);
        }
        k_packh<<<dim3(NRT), dim3(128), 0, stream>>>(hcur, packH);
        k_msgfused<<<dim3(NRT, 4), dim3(512), 0, stream>>>(
            packH, packW + (size_t)l * PWL, gl, ei, off_s, eid_s, msg);
        k_aggfin<<<dim3(NN / 8), dim3(256), 0, stream>>>(
            hcur, msg, off_d, eid_d, invd, rw + (size_t)l * 64 * 64,
            cb + (size_t)l * 64, hnxt);
        float* t = hcur; hcur = hnxt; hnxt = t;
    }

    k_poolhead<<<dim3(NGRAPH), dim3(256), 0, stream>>>(
        hcur, batch, hw1, hb1, hw2, hb2, out);
}

// Round 22
// 311.465 us; speedup vs baseline: 1.0633x; 1.0357x over previous
//
#include <hip/hip_runtime.h>
#include <math.h>

#define NN 10000
#define NE 40000
#define NGRAPH 64
#define HID 64
#define EDIM 16
#define NLAYERS 3

#define NRT 625            // row tiles (16 nodes each)
#define NCT 260            // col tiles: 4096 (B) + 64 (C from b2)
#define WFRAG 512          // shorts per fragment-slot (64 lanes x 8)
#define PWL ((size_t)NCT * 2 * 2 * WFRAG)   // packed W shorts per layer (split-2)

#define GN 32              // nodes per fused group (2 row-tiles)
#define NGRP 313           // ceil(10000/32)
#define KPAD 68            // k-stride in Bt (floats)
#define JSTR (16 * KPAD + 4)   // 1092: j-stride (bank-rotating)
#define MSG_LDS_FLOATS (GN * JSTR + GN * 16)   // 35456 floats = 141824 B

typedef __attribute__((ext_vector_type(8))) short bf8v;
typedef __attribute__((ext_vector_type(4))) float f32x4;

__device__ __forceinline__ float silu_f(float x) { return x / (1.f + expf(-x)); }

__device__ __forceinline__ unsigned short f2bf(float f) {
    unsigned int u = __float_as_uint(f);
    u += 0x7fff + ((u >> 16) & 1);
    return (unsigned short)(u >> 16);
}
__device__ __forceinline__ float bf2f(unsigned short s) {
    return __uint_as_float(((unsigned int)s) << 16);
}
// split-2: v ~= hi + lo, residual ~2^-16 rel; 3 product terms -> out err ~1e-7
// << 1.86e-6 threshold (measured absmax 0.0 in r19/r21).
__device__ __forceinline__ void split2f(float v, short& a, short& b) {
    unsigned short u1 = f2bf(v);      float f1 = bf2f(u1);
    unsigned short u2 = f2bf(v - f1);
    a = (short)u1; b = (short)u2;
}

// ---------------- small row GEMM ----------------
template<int K, bool DO_SILU, bool HAS_BIAS>
__global__ __launch_bounds__(256)
void k_rowmm(const float* __restrict__ A, const float* __restrict__ W,
             const float* __restrict__ bias, float* __restrict__ out, int M) {
    __shared__ float Ws[K * 64];
    __shared__ float As[4 * K];
    const int tid = threadIdx.x;
    for (int idx = tid; idx < K * 64; idx += 256) Ws[idx] = W[idx];
    const int r0 = blockIdx.x * 4;
    for (int idx = tid; idx < 4 * K; idx += 256) {
        int r = r0 + idx / K;
        As[idx] = (r < M) ? A[(size_t)r * K + (idx % K)] : 0.f;
    }
    __syncthreads();
    const int rr = tid >> 6, c = tid & 63;
    const int r = r0 + rr;
    if (r >= M) return;
    float s = HAS_BIAS ? bias[c] : 0.f;
#pragma unroll
    for (int k = 0; k < K; k++) s += As[rr * K + k] * Ws[k * 64 + c];
    if (DO_SILU) s = silu_f(s);
    out[(size_t)r * 64 + c] = s;
}

// ---------------- batched edge-MLP for ALL layers ----------------
__global__ __launch_bounds__(256)
void k_gmm3(const float* __restrict__ ea, const float* __restrict__ ew1,
            const float* __restrict__ eb1, float* __restrict__ g3) {
    const int l = blockIdx.y;
    const float* W = ew1 + (size_t)l * EDIM * 64;
    const float* bias = eb1 + (size_t)l * 64;
    float* out = g3 + (size_t)l * NE * 64;
    __shared__ float Ws[EDIM * 64];
    __shared__ float As[4 * EDIM];
    const int tid = threadIdx.x;
    for (int idx = tid; idx < EDIM * 64; idx += 256) Ws[idx] = W[idx];
    const int r0 = blockIdx.x * 4;
    if (tid < 4 * EDIM) As[tid] = ea[(size_t)r0 * EDIM + tid];
    __syncthreads();
    const int rr = tid >> 6, c = tid & 63;
    float s = bias[c];
#pragma unroll
    for (int k = 0; k < EDIM; k++) s += As[rr * EDIM + k] * Ws[k * 64 + c];
    out[(size_t)(r0 + rr) * 64 + c] = silu_f(s);
}

// ---------------- degree histograms ----------------
__global__ void k_hist(const int* __restrict__ ei, int* __restrict__ cnt_s,
                       int* __restrict__ cnt_d) {
    int e = blockIdx.x * 256 + threadIdx.x;
    if (e >= NE) return;
    atomicAdd(&cnt_s[ei[e]], 1);
    atomicAdd(&cnt_d[ei[NE + e]], 1);
}

// ---------------- single-block: both scans + invdeg ----------------
__global__ __launch_bounds__(1024)
void k_scan2(const int* __restrict__ cnt_s, const int* __restrict__ cnt_d,
             int* __restrict__ off_s, int* __restrict__ off_d,
             int* __restrict__ cur_s, int* __restrict__ cur_d,
             float* __restrict__ invd) {
    __shared__ int part[1024];
    const int t = threadIdx.x;
    const int CH = (NN + 1023) / 1024;
    const int base0 = t * CH;
#pragma unroll
    for (int pass = 0; pass < 2; ++pass) {
        const int* cnt = pass ? cnt_d : cnt_s;
        int* off = pass ? off_d : off_s;
        int* cur = pass ? cur_d : cur_s;
        int s = 0;
        for (int i = 0; i < CH; i++) {
            int idx = base0 + i;
            if (idx < NN) s += cnt[idx];
        }
        part[t] = s;
        __syncthreads();
        for (int d = 1; d < 1024; d <<= 1) {
            int v = (t >= d) ? part[t - d] : 0;
            __syncthreads();
            part[t] += v;
            __syncthreads();
        }
        int run = (t == 0) ? 0 : part[t - 1];
        for (int i = 0; i < CH; i++) {
            int idx = base0 + i;
            if (idx < NN) {
                off[idx] = run;
                int c = cnt[idx];
                if (pass) invd[idx] = (c > 0) ? 1.f / (float)c : 0.f;
                run += c;
                cur[idx] = 0;
            }
        }
        if (t == 1023) off[NN] = run;
        __syncthreads();
    }
}

__global__ void k_fill(const int* __restrict__ keys, const int* __restrict__ off,
                       int* __restrict__ cur, int* __restrict__ eid) {
    int e = blockIdx.x * 256 + threadIdx.x;
    if (e >= NE) return;
    int s = keys[e];
    int p = atomicAdd(&cur[s], 1);
    eid[off[s] + p] = e;
}

// ---------------- pack w2 (+b2 as cols 4096..4159) into MFMA B-fragments ----------
__global__ __launch_bounds__(128)
void k_packw(const float* __restrict__ ew2, const float* __restrict__ eb2,
             short* __restrict__ pw) {
    const int ct = blockIdx.x;
    const int lay = blockIdx.y;
    const int t = threadIdx.x;
    const int l = t & 63, ks = t >> 6;
    const int col = ct * 16 + (l & 15);
    const int i0 = ks * 32 + ((l >> 4) << 3);
    bf8v v1, v2;
#pragma unroll
    for (int tt = 0; tt < 8; ++tt) {
        const int i = i0 + tt;
        float v;
        if (col < 4096)
            v = ew2[(size_t)lay * 262144 + (size_t)(col >> 6) * 4096 + i * 64 + (col & 63)];
        else
            v = eb2[(size_t)lay * 4096 + i * 64 + (col - 4096)];
        short a, b;
        split2f(v, a, b);
        v1[tt] = a; v2[tt] = b;
    }
    short* dst = pw + ((((size_t)lay * NCT + ct) * 2 + ks) * 2) * WFRAG + l * 8;
    *reinterpret_cast<bf8v*>(dst)       = v1;
    *reinterpret_cast<bf8v*>(dst + 512) = v2;
}

// ---------------- pack h into MFMA A-fragments (per layer) ----------------
__global__ __launch_bounds__(128)
void k_packh(const float* __restrict__ h, short* __restrict__ ph) {
    const int rt = blockIdx.x;
    const int t = threadIdx.x;
    const int l = t & 63, ks = t >> 6;
    const int row = rt * 16 + (l & 15);
    const int i0 = ks * 32 + ((l >> 4) << 3);
    const float* hp = h + (size_t)row * 64 + i0;
    bf8v v1, v2;
#pragma unroll
    for (int tt = 0; tt < 8; ++tt) {
        short a, b;
        split2f(hp[tt], a, b);
        v1[tt] = a; v2[tt] = b;
    }
    short* dst = ph + (((size_t)rt * 2 + ks) * 2) * WFRAG + l * 8;
    *reinterpret_cast<bf8v*>(dst)       = v1;
    *reinterpret_cast<bf8v*>(dst + 512) = v2;
}

// ---------------- FUSED v9: GN=32, split-2, no guards (W-L2 traffic halved) ------
// 1024 thr = 16 waves (4/SIMD), 1 block/CU (142KB dyn LDS). Wave wid covers
// k = wid*4..+4; each W-fragment load feeds 12 MFMAs (2 row-tiles). Last group's
// second row-tile is pure garbage in LDS (packH padded; edges only touch j<16).
__global__ __launch_bounds__(1024, 4)
void k_msgfused(const short* __restrict__ ph, const short* __restrict__ pw,
                const float* __restrict__ g, const int* __restrict__ ei,
                const int* __restrict__ csr_off, const int* __restrict__ csr_eid,
                float* __restrict__ msg) {
    extern __shared__ float lds[];
    float* Bt  = lds;                    // [32][JSTR]
    float* C_s = lds + GN * JSTR;        // [32][16]

    const int grp = blockIdx.x, q = blockIdx.y;
    const int n0  = grp * GN;
    const int lane = threadIdx.x & 63;
    const int wid  = threadIdx.x >> 6;   // 0..15
    const int rt0 = grp * 2;

    // A fragments (hi,lo) for both row-tiles (packH padded: rt0+1=625 reads pad)
    bf8v A[2][2][2];
#pragma unroll
    for (int rt2 = 0; rt2 < 2; ++rt2)
#pragma unroll
        for (int ks = 0; ks < 2; ++ks)
#pragma unroll
            for (int sp = 0; sp < 2; ++sp)
                A[rt2][ks][sp] = *reinterpret_cast<const bf8v*>(
                    ph + (((size_t)(rt0 + rt2) * 2 + ks) * 2 + sp) * WFRAG + lane * 8);

    const int oq_w = lane & 15;          // C/D col within quarter
    const int jb   = (lane >> 4) << 2;   // C/D row base

    // ---- MFMA phase: wave wid covers k = wid*4 .. +4 ----
#pragma unroll
    for (int kk = 0; kk < 4; ++kk) {
        const int k = wid * 4 + kk;
        const int ct = k * 4 + q;
        bf8v Bf[2][2];
#pragma unroll
        for (int ks = 0; ks < 2; ++ks)
#pragma unroll
            for (int sp = 0; sp < 2; ++sp)
                Bf[ks][sp] = *reinterpret_cast<const bf8v*>(
                    pw + (((size_t)ct * 2 + ks) * 2 + sp) * WFRAG + lane * 8);
        f32x4 acc0 = {0.f, 0.f, 0.f, 0.f};
        f32x4 acc1 = {0.f, 0.f, 0.f, 0.f};
#pragma unroll
        for (int ks = 0; ks < 2; ++ks) {
            acc0 = __builtin_amdgcn_mfma_f32_16x16x32_bf16(A[0][ks][0], Bf[ks][0], acc0, 0, 0, 0);
            acc0 = __builtin_amdgcn_mfma_f32_16x16x32_bf16(A[0][ks][1], Bf[ks][0], acc0, 0, 0, 0);
            acc0 = __builtin_amdgcn_mfma_f32_16x16x32_bf16(A[0][ks][0], Bf[ks][1], acc0, 0, 0, 0);
            acc1 = __builtin_amdgcn_mfma_f32_16x16x32_bf16(A[1][ks][0], Bf[ks][0], acc1, 0, 0, 0);
            acc1 = __builtin_amdgcn_mfma_f32_16x16x32_bf16(A[1][ks][1], Bf[ks][0], acc1, 0, 0, 0);
            acc1 = __builtin_amdgcn_mfma_f32_16x16x32_bf16(A[1][ks][0], Bf[ks][1], acc1, 0, 0, 0);
        }
#pragma unroll
        for (int r = 0; r < 4; ++r) {
            Bt[(jb + r) * JSTR + oq_w * KPAD + k]        = acc0[r];
            Bt[(16 + jb + r) * JSTR + oq_w * KPAD + k]   = acc1[r];
        }
    }
    if (wid == 15) {   // ---- C tiles (b2 cols) for both row-tiles ----
        const int ct = 256 + q;
        bf8v Bf[2][2];
#pragma unroll
        for (int ks = 0; ks < 2; ++ks)
#pragma unroll
            for (int sp = 0; sp < 2; ++sp)
                Bf[ks][sp] = *reinterpret_cast<const bf8v*>(
                    pw + (((size_t)ct * 2 + ks) * 2 + sp) * WFRAG + lane * 8);
        f32x4 acc0 = {0.f, 0.f, 0.f, 0.f};
        f32x4 acc1 = {0.f, 0.f, 0.f, 0.f};
#pragma unroll
        for (int ks = 0; ks < 2; ++ks) {
            acc0 = __builtin_amdgcn_mfma_f32_16x16x32_bf16(A[0][ks][0], Bf[ks][0], acc0, 0, 0, 0);
            acc0 = __builtin_amdgcn_mfma_f32_16x16x32_bf16(A[0][ks][1], Bf[ks][0], acc0, 0, 0, 0);
            acc0 = __builtin_amdgcn_mfma_f32_16x16x32_bf16(A[0][ks][0], Bf[ks][1], acc0, 0, 0, 0);
            acc1 = __builtin_amdgcn_mfma_f32_16x16x32_bf16(A[1][ks][0], Bf[ks][0], acc1, 0, 0, 0);
            acc1 = __builtin_amdgcn_mfma_f32_16x16x32_bf16(A[1][ks][1], Bf[ks][0], acc1, 0, 0, 0);
            acc1 = __builtin_amdgcn_mfma_f32_16x16x32_bf16(A[1][ks][0], Bf[ks][1], acc1, 0, 0, 0);
        }
#pragma unroll
        for (int r = 0; r < 4; ++r) {
            C_s[(jb + r) * 16 + oq_w]        = acc0[r];
            C_s[(16 + jb + r) * 16 + oq_w]   = acc1[r];
        }
    }

    const int P0 = csr_off[n0];                          // uniform scalar loads
    const int nEnd = (n0 + GN < NN) ? n0 + GN : NN;
    const int Etot = csr_off[nEnd] - P0;
    __syncthreads();

    // ---- edge phase: 16 lanes per edge; 64 slots in flight; j = src - n0 ----
    const int oq = threadIdx.x & 15;
    const int eq = threadIdx.x >> 4;     // 0..63
    for (int slot = eq; slot < Etot; slot += 64) {
        const int e = csr_eid[P0 + slot];
        const int j = ei[e] - n0;        // direct src lookup
        const float* grow = g + (size_t)e * 64;
        const float* Bj = Bt + j * JSTR + oq * KPAD;
        float m = C_s[j * 16 + oq];
#pragma unroll
        for (int k4 = 0; k4 < 16; ++k4) {
            const float4 gv = *(const float4*)(grow + k4 * 4);   // quad-broadcast
            const float4 bv = *(const float4*)(Bj + k4 * 4);
            m += gv.x * bv.x + gv.y * bv.y + gv.z * bv.z + gv.w * bv.w;
        }
        msg[(size_t)e * 64 + q * 16 + oq] = m;
    }
}

// ---------------- gather by dst + root GEMM + silu (8 rows/block) ----------------
__global__ __launch_bounds__(256)
void k_aggfin(const float* __restrict__ h, const float* __restrict__ msg,
              const int* __restrict__ off2, const int* __restrict__ eid2,
              const float* __restrict__ invd, const float* __restrict__ rw,
              const float* __restrict__ cb, float* __restrict__ hout) {
    __shared__ float Ws[64 * 64];
    __shared__ float As[8 * 64];
    __shared__ int eoff[9];
    const int tid = threadIdx.x;
    for (int idx = tid; idx < 64 * 64; idx += 256) Ws[idx] = rw[idx];
    const int r0 = blockIdx.x * 8;
    for (int idx = tid; idx < 8 * 64; idx += 256) As[idx] = h[(size_t)r0 * 64 + idx];
    if (tid < 9) eoff[tid] = off2[r0 + tid];
    __syncthreads();
    const int rr = tid >> 6, c = tid & 63;
#pragma unroll
    for (int half = 0; half < 2; ++half) {
        const int lr = half * 4 + rr;
        const int r = r0 + lr;
        float a = 0.f;
        for (int p = eoff[lr]; p < eoff[lr + 1]; ++p) {
            a += msg[(size_t)eid2[p] * 64 + c];
        }
        float s = cb[c] + a * invd[r];
        const float* Ar = As + lr * 64;
#pragma unroll
        for (int k = 0; k < 64; k++) s += Ar[k] * Ws[k * 64 + c];
        hout[(size_t)r * 64 + c] = silu_f(s);
    }
}

// ---------------- fused mean-pool + head MLP ----------------
__global__ __launch_bounds__(256)
void k_poolhead(const float* __restrict__ h, const int* __restrict__ batch,
                const float* __restrict__ w1, const float* __restrict__ b1,
                const float* __restrict__ w2, const float* __restrict__ b2,
                float* __restrict__ out) {
    __shared__ float part[4 * 64];
    __shared__ float hrow[64];
    const int gidx = blockIdx.x;
    const int tid = threadIdx.x;
    const int r = tid >> 6, o = tid & 63;
    int lo = 0, hi = NN;
    while (lo < hi) { int m = (lo + hi) >> 1; if (batch[m] < gidx) lo = m + 1; else hi = m; }
    const int beg = lo;
    hi = NN;
    while (lo < hi) { int m = (lo + hi) >> 1; if (batch[m] < gidx + 1) lo = m + 1; else hi = m; }
    const int end = lo;
    float acc = 0.f;
    for (int n = beg + r; n < end; n += 4) acc += h[(size_t)n * 64 + o];
    part[r * 64 + o] = acc;
    __syncthreads();
    if (tid < 64) {
        const int cnt = end - beg;
        const float inv = (cnt > 0) ? 1.f / (float)cnt : 1.f;
        hrow[tid] = (part[tid] + part[64 + tid] + part[128 + tid] + part[192 + tid]) * inv;
    }
    __syncthreads();
    if (tid < 64) {
        float s = b1[tid];
#pragma unroll
        for (int k = 0; k < 64; ++k) s += hrow[k] * w1[k * 64 + tid];
        s = silu_f(s);
        float v = s * w2[tid];
#pragma unroll
        for (int d = 32; d > 0; d >>= 1) v += __shfl_down(v, d);
        if (tid == 0) out[gidx] = v + b2[0];
    }
}

extern "C" void kernel_launch(void* const* d_in, const int* in_sizes, int n_in,
                              void* d_out, int out_size, void* d_ws, size_t ws_size,
                              hipStream_t stream) {
    const float* x     = (const float*)d_in[0];
    const float* ea    = (const float*)d_in[1];
    const int*   ei    = (const int*)  d_in[2];
    const int*   batch = (const int*)  d_in[3];
    const float* pw    = (const float*)d_in[4];
    const float* pb    = (const float*)d_in[5];
    const float* ew1   = (const float*)d_in[6];
    const float* eb1   = (const float*)d_in[7];
    const float* ew2   = (const float*)d_in[8];
    const float* eb2   = (const float*)d_in[9];
    const float* rw    = (const float*)d_in[10];
    const float* cb    = (const float*)d_in[11];
    const float* hw1   = (const float*)d_in[12];
    const float* hb1   = (const float*)d_in[13];
    const float* hw2   = (const float*)d_in[14];
    const float* hb2   = (const float*)d_in[15];
    float* out = (float*)d_out;

    float* ws = (float*)d_ws;
    size_t off = 0;
    auto alloc = [&](size_t n) {
        float* p = ws + off;
        off += (n + 63) & ~(size_t)63;
        return p;
    };
    float* hA   = alloc((size_t)NN * 64);
    float* hBuf = alloc((size_t)NN * 64);
    float* msg  = alloc((size_t)NE * 64);
    float* invd = alloc(NN);
    int* off_s = (int*)alloc(NN + 1);
    int* off_d = (int*)alloc(NN + 1);
    int* cnt_s = (int*)alloc(NN);
    int* cnt_d = (int*)alloc(NN);
    int* cur_s = (int*)alloc(NN);
    int* cur_d = (int*)alloc(NN);
    int* eid_s = (int*)alloc(NE);
    int* eid_d = (int*)alloc(NE);
    short* packW = (short*)alloc(3 * PWL / 2 + 64);
    short* packH = (short*)alloc((size_t)(NRT + 1) * 2 * 2 * WFRAG / 2 + 64);  // +1 pad tile

    const size_t needG3 = (size_t)3 * NE * 64;
    bool batchG = (off + needG3 + 128) * sizeof(float) <= ws_size;
    float* gbuf = alloc(batchG ? needG3 : (size_t)NE * 64);

    const size_t MSG_LDS_BYTES = (size_t)MSG_LDS_FLOATS * sizeof(float);  // 141824
    hipFuncSetAttribute(reinterpret_cast<const void*>(k_msgfused),
                        hipFuncAttributeMaxDynamicSharedMemorySize, (int)MSG_LDS_BYTES);

    hipMemsetAsync(cnt_s, 0, NN * sizeof(int), stream);
    hipMemsetAsync(cnt_d, 0, NN * sizeof(int), stream);
    // zero the packH pad tile so garbage A-frags are finite (MFMA on any bits is
    // safe, but keep it deterministic)
    hipMemsetAsync(packH + (size_t)NRT * 2 * 2 * WFRAG, 0, 2 * 2 * WFRAG * sizeof(short), stream);

    k_hist<<<dim3((NE + 255) / 256), dim3(256), 0, stream>>>(ei, cnt_s, cnt_d);
    k_scan2<<<dim3(1), dim3(1024), 0, stream>>>(cnt_s, cnt_d, off_s, off_d,
                                                cur_s, cur_d, invd);
    k_fill<<<dim3((NE + 255) / 256), dim3(256), 0, stream>>>(ei, off_s, cur_s, eid_s);
    k_fill<<<dim3((NE + 255) / 256), dim3(256), 0, stream>>>(ei + NE, off_d, cur_d, eid_d);

    k_packw<<<dim3(NCT, 3), dim3(128), 0, stream>>>(ew2, eb2, packW);

    k_rowmm<64, false, true><<<dim3(NN / 4), dim3(256), 0, stream>>>(x, pw, pb, hA, NN);

    if (batchG) {
        k_gmm3<<<dim3(NE / 4, 3), dim3(256), 0, stream>>>(ea, ew1, eb1, gbuf);
    }

    float* hcur = hA;
    float* hnxt = hBuf;
    for (int l = 0; l < NLAYERS; l++) {
        float* gl = batchG ? gbuf + (size_t)l * NE * 64 : gbuf;
        if (!batchG) {
            k_rowmm<16, true, true><<<dim3(NE / 4), dim3(256), 0, stream>>>(
                ea, ew1 + (size_t)l * EDIM * 64, eb1 + (size_t)l * 64, gl, NE);
        }
        k_packh<<<dim3(NRT), dim3(128), 0, stream>>>(hcur, packH);
        k_msgfused<<<dim3(NGRP, 4), dim3(1024), MSG_LDS_BYTES, stream>>>(
            packH, packW + (size_t)l * PWL, gl, ei, off_s, eid_s, msg);
        k_aggfin<<<dim3(NN / 8), dim3(256), 0, stream>>>(
            hcur, msg, off_d, eid_d, invd, rw + (size_t)l * 64 * 64,
            cb + (size_t)l * 64, hnxt);
        float* t = hcur; hcur = hnxt; hnxt = t;
    }

    k_poolhead<<<dim3(NGRAPH), dim3(256), 0, stream>>>(
        hcur, batch, hw1, hb1, hw2, hb2, out);
}

// Round 23
// 305.533 us; speedup vs baseline: 1.0839x; 1.0194x over previous
//
#include <hip/hip_runtime.h>
#include <math.h>

#define NN 10000
#define NE 40000
#define NGRAPH 64
#define HID 64
#define EDIM 16
#define NLAYERS 3

#define NRT 625            // row tiles (16 nodes each)
#define NCT 260            // col tiles: 4096 (B) + 64 (C from b2)
#define WFRAG 512          // shorts per fragment-slot (64 lanes x 8)
#define PWL ((size_t)NCT * 2 * 2 * WFRAG)   // packed W shorts per layer (split-2)

#define GN 32              // nodes per fused group (2 row-tiles)
#define NGRP 313           // ceil(10000/32)
#define KPAD 68            // k-stride in Bt (floats)
#define JSTR (16 * KPAD + 4)   // 1092: j-stride
#define MSG_LDS_FLOATS (GN * JSTR + GN * 16)   // 35456 floats = 141824 B

typedef __attribute__((ext_vector_type(8))) short bf8v;
typedef __attribute__((ext_vector_type(4))) float f32x4;

__device__ __forceinline__ float silu_f(float x) { return x / (1.f + expf(-x)); }

__device__ __forceinline__ unsigned short f2bf(float f) {
    unsigned int u = __float_as_uint(f);
    u += 0x7fff + ((u >> 16) & 1);
    return (unsigned short)(u >> 16);
}
__device__ __forceinline__ float bf2f(unsigned short s) {
    return __uint_as_float(((unsigned int)s) << 16);
}
// split-2: v ~= hi + lo; 3 product terms -> out err ~1e-7 << 1.86e-6 threshold
// (measured absmax 0.0 in r19/r21/r22).
__device__ __forceinline__ void split2f(float v, short& a, short& b) {
    unsigned short u1 = f2bf(v);      float f1 = bf2f(u1);
    unsigned short u2 = f2bf(v - f1);
    a = (short)u1; b = (short)u2;
}

// write one h element (row r, dim c) into packed-A fragment layout
__device__ __forceinline__ void pack_elem(short* __restrict__ ph, int r, int c, float v) {
    const int rt = r >> 4;
    const int l  = (r & 15) | (((c >> 3) & 3) << 4);
    const int ks = c >> 5;
    const int tt = c & 7;
    short hi, lo;
    split2f(v, hi, lo);
    short* dst = ph + (((size_t)rt * 2 + ks) * 2) * WFRAG + l * 8 + tt;
    dst[0]   = hi;
    dst[512] = lo;   // sp=1 slot (+WFRAG)
}

// ---------------- small row GEMM (optionally packs output into MFMA A-frags) ----
template<int K, bool DO_SILU, bool HAS_BIAS, bool PACK>
__global__ __launch_bounds__(256)
void k_rowmm(const float* __restrict__ A, const float* __restrict__ W,
             const float* __restrict__ bias, float* __restrict__ out,
             short* __restrict__ ph, int M) {
    __shared__ float Ws[K * 64];
    __shared__ float As[4 * K];
    const int tid = threadIdx.x;
    for (int idx = tid; idx < K * 64; idx += 256) Ws[idx] = W[idx];
    const int r0 = blockIdx.x * 4;
    for (int idx = tid; idx < 4 * K; idx += 256) {
        int r = r0 + idx / K;
        As[idx] = (r < M) ? A[(size_t)r * K + (idx % K)] : 0.f;
    }
    __syncthreads();
    const int rr = tid >> 6, c = tid & 63;
    const int r = r0 + rr;
    if (r >= M) return;
    float s = HAS_BIAS ? bias[c] : 0.f;
#pragma unroll
    for (int k = 0; k < K; k++) s += As[rr * K + k] * Ws[k * 64 + c];
    if (DO_SILU) s = silu_f(s);
    out[(size_t)r * 64 + c] = s;
    if (PACK) pack_elem(ph, r, c, s);
}

// ---------------- batched edge-MLP for ALL layers ----------------
__global__ __launch_bounds__(256)
void k_gmm3(const float* __restrict__ ea, const float* __restrict__ ew1,
            const float* __restrict__ eb1, float* __restrict__ g3) {
    const int l = blockIdx.y;
    const float* W = ew1 + (size_t)l * EDIM * 64;
    const float* bias = eb1 + (size_t)l * 64;
    float* out = g3 + (size_t)l * NE * 64;
    __shared__ float Ws[EDIM * 64];
    __shared__ float As[4 * EDIM];
    const int tid = threadIdx.x;
    for (int idx = tid; idx < EDIM * 64; idx += 256) Ws[idx] = W[idx];
    const int r0 = blockIdx.x * 4;
    if (tid < 4 * EDIM) As[tid] = ea[(size_t)r0 * EDIM + tid];
    __syncthreads();
    const int rr = tid >> 6, c = tid & 63;
    float s = bias[c];
#pragma unroll
    for (int k = 0; k < EDIM; k++) s += As[rr * EDIM + k] * Ws[k * 64 + c];
    out[(size_t)(r0 + rr) * 64 + c] = silu_f(s);
}

// ---------------- degree histograms ----------------
__global__ void k_hist(const int* __restrict__ ei, int* __restrict__ cnt_s,
                       int* __restrict__ cnt_d) {
    int e = blockIdx.x * 256 + threadIdx.x;
    if (e >= NE) return;
    atomicAdd(&cnt_s[ei[e]], 1);
    atomicAdd(&cnt_d[ei[NE + e]], 1);
}

// ---------------- single-block: both scans + invdeg ----------------
__global__ __launch_bounds__(1024)
void k_scan2(const int* __restrict__ cnt_s, const int* __restrict__ cnt_d,
             int* __restrict__ off_s, int* __restrict__ off_d,
             int* __restrict__ cur_s, int* __restrict__ cur_d,
             float* __restrict__ invd) {
    __shared__ int part[1024];
    const int t = threadIdx.x;
    const int CH = (NN + 1023) / 1024;
    const int base0 = t * CH;
#pragma unroll
    for (int pass = 0; pass < 2; ++pass) {
        const int* cnt = pass ? cnt_d : cnt_s;
        int* off = pass ? off_d : off_s;
        int* cur = pass ? cur_d : cur_s;
        int s = 0;
        for (int i = 0; i < CH; i++) {
            int idx = base0 + i;
            if (idx < NN) s += cnt[idx];
        }
        part[t] = s;
        __syncthreads();
        for (int d = 1; d < 1024; d <<= 1) {
            int v = (t >= d) ? part[t - d] : 0;
            __syncthreads();
            part[t] += v;
            __syncthreads();
        }
        int run = (t == 0) ? 0 : part[t - 1];
        for (int i = 0; i < CH; i++) {
            int idx = base0 + i;
            if (idx < NN) {
                off[idx] = run;
                int c = cnt[idx];
                if (pass) invd[idx] = (c > 0) ? 1.f / (float)c : 0.f;
                run += c;
                cur[idx] = 0;
            }
        }
        if (t == 1023) off[NN] = run;
        __syncthreads();
    }
}

__global__ void k_fill(const int* __restrict__ keys, const int* __restrict__ off,
                       int* __restrict__ cur, int* __restrict__ eid) {
    int e = blockIdx.x * 256 + threadIdx.x;
    if (e >= NE) return;
    int s = keys[e];
    int p = atomicAdd(&cur[s], 1);
    eid[off[s] + p] = e;
}

// ---------------- pack w2 (+b2 as cols 4096..4159) into MFMA B-fragments ----------
__global__ __launch_bounds__(128)
void k_packw(const float* __restrict__ ew2, const float* __restrict__ eb2,
             short* __restrict__ pw) {
    const int ct = blockIdx.x;
    const int lay = blockIdx.y;
    const int t = threadIdx.x;
    const int l = t & 63, ks = t >> 6;
    const int col = ct * 16 + (l & 15);
    const int i0 = ks * 32 + ((l >> 4) << 3);
    bf8v v1, v2;
#pragma unroll
    for (int tt = 0; tt < 8; ++tt) {
        const int i = i0 + tt;
        float v;
        if (col < 4096)
            v = ew2[(size_t)lay * 262144 + (size_t)(col >> 6) * 4096 + i * 64 + (col & 63)];
        else
            v = eb2[(size_t)lay * 4096 + i * 64 + (col - 4096)];
        short a, b;
        split2f(v, a, b);
        v1[tt] = a; v2[tt] = b;
    }
    short* dst = pw + ((((size_t)lay * NCT + ct) * 2 + ks) * 2) * WFRAG + l * 8;
    *reinterpret_cast<bf8v*>(dst)       = v1;
    *reinterpret_cast<bf8v*>(dst + 512) = v2;
}

// ---------------- FUSED v9 (r22 winner): GN=32, split-2, no guards ----------------
__global__ __launch_bounds__(1024, 4)
void k_msgfused(const short* __restrict__ ph, const short* __restrict__ pw,
                const float* __restrict__ g, const int* __restrict__ ei,
                const int* __restrict__ csr_off, const int* __restrict__ csr_eid,
                float* __restrict__ msg) {
    extern __shared__ float lds[];
    float* Bt  = lds;                    // [32][JSTR]
    float* C_s = lds + GN * JSTR;        // [32][16]

    const int grp = blockIdx.x, q = blockIdx.y;
    const int n0  = grp * GN;
    const int lane = threadIdx.x & 63;
    const int wid  = threadIdx.x >> 6;   // 0..15
    const int rt0 = grp * 2;

    bf8v A[2][2][2];
#pragma unroll
    for (int rt2 = 0; rt2 < 2; ++rt2)
#pragma unroll
        for (int ks = 0; ks < 2; ++ks)
#pragma unroll
            for (int sp = 0; sp < 2; ++sp)
                A[rt2][ks][sp] = *reinterpret_cast<const bf8v*>(
                    ph + (((size_t)(rt0 + rt2) * 2 + ks) * 2 + sp) * WFRAG + lane * 8);

    const int oq_w = lane & 15;
    const int jb   = (lane >> 4) << 2;

#pragma unroll
    for (int kk = 0; kk < 4; ++kk) {
        const int k = wid * 4 + kk;
        const int ct = k * 4 + q;
        bf8v Bf[2][2];
#pragma unroll
        for (int ks = 0; ks < 2; ++ks)
#pragma unroll
            for (int sp = 0; sp < 2; ++sp)
                Bf[ks][sp] = *reinterpret_cast<const bf8v*>(
                    pw + (((size_t)ct * 2 + ks) * 2 + sp) * WFRAG + lane * 8);
        f32x4 acc0 = {0.f, 0.f, 0.f, 0.f};
        f32x4 acc1 = {0.f, 0.f, 0.f, 0.f};
#pragma unroll
        for (int ks = 0; ks < 2; ++ks) {
            acc0 = __builtin_amdgcn_mfma_f32_16x16x32_bf16(A[0][ks][0], Bf[ks][0], acc0, 0, 0, 0);
            acc0 = __builtin_amdgcn_mfma_f32_16x16x32_bf16(A[0][ks][1], Bf[ks][0], acc0, 0, 0, 0);
            acc0 = __builtin_amdgcn_mfma_f32_16x16x32_bf16(A[0][ks][0], Bf[ks][1], acc0, 0, 0, 0);
            acc1 = __builtin_amdgcn_mfma_f32_16x16x32_bf16(A[1][ks][0], Bf[ks][0], acc1, 0, 0, 0);
            acc1 = __builtin_amdgcn_mfma_f32_16x16x32_bf16(A[1][ks][1], Bf[ks][0], acc1, 0, 0, 0);
            acc1 = __builtin_amdgcn_mfma_f32_16x16x32_bf16(A[1][ks][0], Bf[ks][1], acc1, 0, 0, 0);
        }
#pragma unroll
        for (int r = 0; r < 4; ++r) {
            Bt[(jb + r) * JSTR + oq_w * KPAD + k]      = acc0[r];
            Bt[(16 + jb + r) * JSTR + oq_w * KPAD + k] = acc1[r];
        }
    }
    if (wid == 15) {
        const int ct = 256 + q;
        bf8v Bf[2][2];
#pragma unroll
        for (int ks = 0; ks < 2; ++ks)
#pragma unroll
            for (int sp = 0; sp < 2; ++sp)
                Bf[ks][sp] = *reinterpret_cast<const bf8v*>(
                    pw + (((size_t)ct * 2 + ks) * 2 + sp) * WFRAG + lane * 8);
        f32x4 acc0 = {0.f, 0.f, 0.f, 0.f};
        f32x4 acc1 = {0.f, 0.f, 0.f, 0.f};
#pragma unroll
        for (int ks = 0; ks < 2; ++ks) {
            acc0 = __builtin_amdgcn_mfma_f32_16x16x32_bf16(A[0][ks][0], Bf[ks][0], acc0, 0, 0, 0);
            acc0 = __builtin_amdgcn_mfma_f32_16x16x32_bf16(A[0][ks][1], Bf[ks][0], acc0, 0, 0, 0);
            acc0 = __builtin_amdgcn_mfma_f32_16x16x32_bf16(A[0][ks][0], Bf[ks][1], acc0, 0, 0, 0);
            acc1 = __builtin_amdgcn_mfma_f32_16x16x32_bf16(A[1][ks][0], Bf[ks][0], acc1, 0, 0, 0);
            acc1 = __builtin_amdgcn_mfma_f32_16x16x32_bf16(A[1][ks][1], Bf[ks][0], acc1, 0, 0, 0);
            acc1 = __builtin_amdgcn_mfma_f32_16x16x32_bf16(A[1][ks][0], Bf[ks][1], acc1, 0, 0, 0);
        }
#pragma unroll
        for (int r = 0; r < 4; ++r) {
            C_s[(jb + r) * 16 + oq_w]      = acc0[r];
            C_s[(16 + jb + r) * 16 + oq_w] = acc1[r];
        }
    }

    const int P0 = csr_off[n0];
    const int nEnd = (n0 + GN < NN) ? n0 + GN : NN;
    const int Etot = csr_off[nEnd] - P0;
    __syncthreads();

    const int oq = threadIdx.x & 15;
    const int eq = threadIdx.x >> 4;
    for (int slot = eq; slot < Etot; slot += 64) {
        const int e = csr_eid[P0 + slot];
        const int j = ei[e] - n0;
        const float* grow = g + (size_t)e * 64;
        const float* Bj = Bt + j * JSTR + oq * KPAD;
        float m = C_s[j * 16 + oq];
#pragma unroll
        for (int k4 = 0; k4 < 16; ++k4) {
            const float4 gv = *(const float4*)(grow + k4 * 4);
            const float4 bv = *(const float4*)(Bj + k4 * 4);
            m += gv.x * bv.x + gv.y * bv.y + gv.z * bv.z + gv.w * bv.w;
        }
        msg[(size_t)e * 64 + q * 16 + oq] = m;
    }
}

// ---------------- gather by dst + root GEMM + silu + fused A-frag pack ----------
template<bool PACK>
__global__ __launch_bounds__(256)
void k_aggfin(const float* __restrict__ h, const float* __restrict__ msg,
              const int* __restrict__ off2, const int* __restrict__ eid2,
              const float* __restrict__ invd, const float* __restrict__ rw,
              const float* __restrict__ cb, float* __restrict__ hout,
              short* __restrict__ ph) {
    __shared__ float Ws[64 * 64];
    __shared__ float As[8 * 64];
    __shared__ int eoff[9];
    const int tid = threadIdx.x;
    for (int idx = tid; idx < 64 * 64; idx += 256) Ws[idx] = rw[idx];
    const int r0 = blockIdx.x * 8;
    for (int idx = tid; idx < 8 * 64; idx += 256) As[idx] = h[(size_t)r0 * 64 + idx];
    if (tid < 9) eoff[tid] = off2[r0 + tid];
    __syncthreads();
    const int rr = tid >> 6, c = tid & 63;
#pragma unroll
    for (int half = 0; half < 2; ++half) {
        const int lr = half * 4 + rr;
        const int r = r0 + lr;
        float a = 0.f;
        for (int p = eoff[lr]; p < eoff[lr + 1]; ++p) {
            a += msg[(size_t)eid2[p] * 64 + c];
        }
        float s = cb[c] + a * invd[r];
        const float* Ar = As + lr * 64;
#pragma unroll
        for (int k = 0; k < 64; k++) s += Ar[k] * Ws[k * 64 + c];
        s = silu_f(s);
        hout[(size_t)r * 64 + c] = s;
        if (PACK) pack_elem(ph, r, c, s);
    }
}

// ---------------- fused mean-pool + head MLP ----------------
__global__ __launch_bounds__(256)
void k_poolhead(const float* __restrict__ h, const int* __restrict__ batch,
                const float* __restrict__ w1, const float* __restrict__ b1,
                const float* __restrict__ w2, const float* __restrict__ b2,
                float* __restrict__ out) {
    __shared__ float part[4 * 64];
    __shared__ float hrow[64];
    const int gidx = blockIdx.x;
    const int tid = threadIdx.x;
    const int r = tid >> 6, o = tid & 63;
    int lo = 0, hi = NN;
    while (lo < hi) { int m = (lo + hi) >> 1; if (batch[m] < gidx) lo = m + 1; else hi = m; }
    const int beg = lo;
    hi = NN;
    while (lo < hi) { int m = (lo + hi) >> 1; if (batch[m] < gidx + 1) lo = m + 1; else hi = m; }
    const int end = lo;
    float acc = 0.f;
    for (int n = beg + r; n < end; n += 4) acc += h[(size_t)n * 64 + o];
    part[r * 64 + o] = acc;
    __syncthreads();
    if (tid < 64) {
        const int cnt = end - beg;
        const float inv = (cnt > 0) ? 1.f / (float)cnt : 1.f;
        hrow[tid] = (part[tid] + part[64 + tid] + part[128 + tid] + part[192 + tid]) * inv;
    }
    __syncthreads();
    if (tid < 64) {
        float s = b1[tid];
#pragma unroll
        for (int k = 0; k < 64; ++k) s += hrow[k] * w1[k * 64 + tid];
        s = silu_f(s);
        float v = s * w2[tid];
#pragma unroll
        for (int d = 32; d > 0; d >>= 1) v += __shfl_down(v, d);
        if (tid == 0) out[gidx] = v + b2[0];
    }
}

extern "C" void kernel_launch(void* const* d_in, const int* in_sizes, int n_in,
                              void* d_out, int out_size, void* d_ws, size_t ws_size,
                              hipStream_t stream) {
    const float* x     = (const float*)d_in[0];
    const float* ea    = (const float*)d_in[1];
    const int*   ei    = (const int*)  d_in[2];
    const int*   batch = (const int*)  d_in[3];
    const float* pw    = (const float*)d_in[4];
    const float* pb    = (const float*)d_in[5];
    const float* ew1   = (const float*)d_in[6];
    const float* eb1   = (const float*)d_in[7];
    const float* ew2   = (const float*)d_in[8];
    const float* eb2   = (const float*)d_in[9];
    const float* rw    = (const float*)d_in[10];
    const float* cb    = (const float*)d_in[11];
    const float* hw1   = (const float*)d_in[12];
    const float* hb1   = (const float*)d_in[13];
    const float* hw2   = (const float*)d_in[14];
    const float* hb2   = (const float*)d_in[15];
    float* out = (float*)d_out;

    float* ws = (float*)d_ws;
    size_t off = 0;
    auto alloc = [&](size_t n) {
        float* p = ws + off;
        off += (n + 63) & ~(size_t)63;
        return p;
    };
    float* hA   = alloc((size_t)NN * 64);
    float* hBuf = alloc((size_t)NN * 64);
    float* msg  = alloc((size_t)NE * 64);
    float* invd = alloc(NN);
    int* off_s = (int*)alloc(NN + 1);
    int* off_d = (int*)alloc(NN + 1);
    int* cnt_s = (int*)alloc(NN);
    int* cnt_d = (int*)alloc(NN);
    int* cur_s = (int*)alloc(NN);
    int* cur_d = (int*)alloc(NN);
    int* eid_s = (int*)alloc(NE);
    int* eid_d = (int*)alloc(NE);
    short* packW = (short*)alloc(3 * PWL / 2 + 64);
    short* packH = (short*)alloc((size_t)(NRT + 1) * 2 * 2 * WFRAG / 2 + 64);  // +1 pad tile

    const size_t needG3 = (size_t)3 * NE * 64;
    bool batchG = (off + needG3 + 128) * sizeof(float) <= ws_size;
    float* gbuf = alloc(batchG ? needG3 : (size_t)NE * 64);

    const size_t MSG_LDS_BYTES = (size_t)MSG_LDS_FLOATS * sizeof(float);  // 141824
    hipFuncSetAttribute(reinterpret_cast<const void*>(k_msgfused),
                        hipFuncAttributeMaxDynamicSharedMemorySize, (int)MSG_LDS_BYTES);

    hipMemsetAsync(cnt_s, 0, NN * sizeof(int), stream);
    hipMemsetAsync(cnt_d, 0, NN * sizeof(int), stream);
    // zero the packH pad tile (rt=625) so garbage A-frags stay deterministic
    hipMemsetAsync(packH + (size_t)NRT * 2 * 2 * WFRAG, 0, 2 * 2 * WFRAG * sizeof(short), stream);

    k_hist<<<dim3((NE + 255) / 256), dim3(256), 0, stream>>>(ei, cnt_s, cnt_d);
    k_scan2<<<dim3(1), dim3(1024), 0, stream>>>(cnt_s, cnt_d, off_s, off_d,
                                                cur_s, cur_d, invd);
    k_fill<<<dim3((NE + 255) / 256), dim3(256), 0, stream>>>(ei, off_s, cur_s, eid_s);
    k_fill<<<dim3((NE + 255) / 256), dim3(256), 0, stream>>>(ei + NE, off_d, cur_d, eid_d);

    k_packw<<<dim3(NCT, 3), dim3(128), 0, stream>>>(ew2, eb2, packW);

    // h = x @ proj_w + proj_b  (+ packed A-frags for layer 0)
    k_rowmm<64, false, true, true><<<dim3(NN / 4), dim3(256), 0, stream>>>(
        x, pw, pb, hA, packH, NN);

    if (batchG) {
        k_gmm3<<<dim3(NE / 4, 3), dim3(256), 0, stream>>>(ea, ew1, eb1, gbuf);
    }

    float* hcur = hA;
    float* hnxt = hBuf;
    for (int l = 0; l < NLAYERS; l++) {
        float* gl = batchG ? gbuf + (size_t)l * NE * 64 : gbuf;
        if (!batchG) {
            k_rowmm<16, true, true, false><<<dim3(NE / 4), dim3(256), 0, stream>>>(
                ea, ew1 + (size_t)l * EDIM * 64, eb1 + (size_t)l * 64, gl, nullptr, NE);
        }
        k_msgfused<<<dim3(NGRP, 4), dim3(1024), MSG_LDS_BYTES, stream>>>(
            packH, packW + (size_t)l * PWL, gl, ei, off_s, eid_s, msg);
        if (l < NLAYERS - 1) {
            k_aggfin<true><<<dim3(NN / 8), dim3(256), 0, stream>>>(
                hcur, msg, off_d, eid_d, invd, rw + (size_t)l * 64 * 64,
                cb + (size_t)l * 64, hnxt, packH);
        } else {
            k_aggfin<false><<<dim3(NN / 8), dim3(256), 0, stream>>>(
                hcur, msg, off_d, eid_d, invd, rw + (size_t)l * 64 * 64,
                cb + (size_t)l * 64, hnxt, nullptr);
        }
        float* t = hcur; hcur = hnxt; hnxt = t;
    }

    k_poolhead<<<dim3(NGRAPH), dim3(256), 0, stream>>>(
        hcur, batch, hw1, hb1, hw2, hb2, out);
}